// Round 10
// baseline (231.719 us; speedup 1.0000x reference)
//
#include <hip/hip_runtime.h>

#define H_ 56
#define W_ 56
#define HW_ 3136
#define CIN_ 256
#define COUT_ 256

typedef __attribute__((ext_vector_type(8))) short short8;
typedef __attribute__((ext_vector_type(4))) float f32x4;

// Fragment-ordered bf16 weights (B-operand layout), written by prep_weights.
// idx = ((((bo*2+wo)*8+ks)*4+b)*64+lane)*8+j holds
//   W[bo*128 + wo*64 + b*16 + (lane&15)][ks*32 + j*4 + (lane>>4)]
// k-permutation c = ks*32 + 4j + quad applied identically to both operands
// (any k-permutation leaves the GEMM sum unchanged); it makes each unrolled
// x-gather load's shift-region compile-time except 3 straddle cells.
__device__ unsigned short g_wbf[COUT_ * CIN_];

__device__ __forceinline__ unsigned short f2bf(float f) {
  union { float f; unsigned int i; } v; v.f = f;
  unsigned int b = v.i + (0x7fffu + ((v.i >> 16) & 1u));  // RNE
  return (unsigned short)(b >> 16);
}

__global__ __launch_bounds__(256)
void prep_weights(const float* __restrict__ wgt) {
  int idx  = blockIdx.x * 256 + threadIdx.x;   // 0..65535
  int j    = idx & 7;
  int lane = (idx >> 3) & 63;
  int b    = (idx >> 9) & 3;
  int ks   = (idx >> 11) & 7;
  int wo   = (idx >> 14) & 1;
  int bo   = idx >> 15;
  int o = bo * 128 + wo * 64 + b * 16 + (lane & 15);
  int k = ks * 32 + j * 4 + (lane >> 4);
  g_wbf[idx] = f2bf(wgt[o * CIN_ + k]);
}

__global__ __launch_bounds__(256, 4)
void shiftconv_gemm(const float* __restrict__ x,
                    const float* __restrict__ gamma,
                    const float* __restrict__ beta,
                    const float* __restrict__ rmean,
                    const float* __restrict__ rvar,
                    float* __restrict__ out)
{
  // NO main-loop LDS, NO main-loop barriers. LDS only: BN params + wave-private
  // epilogue transpose buffer (33-padded -> 2-way banked reads).
  __shared__ float bnp[256];
  __shared__ float tbuf[4][32 * 33];

  const int t = threadIdx.x;
  // XCD-bijective swizzle (nwg = 3136 = 8*392): bo-pairs (same bn -> same x
  // slice) land adjacent on the same XCD (verified: FETCH 137->61->51 MB).
  const int orig = blockIdx.x;
  const int wgid = (orig & 7) * 392 + (orig >> 3);
  const int bo   = wgid & 1;     // 2 o-tiles of 128
  const int bn   = wgid >> 1;    // 1568 n-tiles of 64

  const int lane = t & 63;
  const int wv   = t >> 6;
  const int wn   = wv & 1;       // n-half (32 of 64)
  const int wo   = wv >> 1;      // o-half (64 of 128)
  const int quad = lane >> 4;
  const int l15  = lane & 15;

  if (t < 128) {
    int o = bo * 128 + t;
    float inv = gamma[o] * rsqrtf(rvar[o] + 1e-5f);
    bnp[2 * t]     = inv;
    bnp[2 * t + 1] = beta[o] - rmean[o] * inv;
  }
  __syncthreads();   // only barrier in the kernel

  // ---- x-gather decode: lane owns n = bn*64 + wn*32 + a*16 + l15 (a=0,1) ----
  const int nglob0 = bn * 64;
  const int bidx   = nglob0 / HW_;          // block lies within one image
  const int rem    = nglob0 - bidx * HW_;
  const int hw0    = rem + wn * 32 + l15;   // a=0 flattened hw
  const int hh0    = hw0 / W_;
  const int ww0    = hw0 - hh0 * W_;
  const int hw1    = hw0 + 16;              // a=1 is +16 positions
  const int hh1    = hw1 / W_;
  const int ww1    = hw1 - hh1 * W_;

  // Per-region CLAMPED byte voffsets (quad*HW folded in). Invalid lanes fall
  // back to the region-0 (unshifted, always in-bounds) offset; their loaded
  // value is zeroed by the 0/1 multiplier. This keeps every executed load
  // in-bounds (R9 faulted: value-masking alone still dereferences OOB).
  const int qh = quad * HW_;
  const unsigned int base0 = (unsigned int)((hw0 + qh) * 4);
  const unsigned int base1 = (unsigned int)((hw1 + qh) * 4);
  const bool v0L = (ww0 >= 1),      v1L = (ww1 >= 1);
  const bool v0R = (ww0 <= W_ - 2), v1R = (ww1 <= W_ - 2);
  const bool v0U = (hh0 >= 1),      v1U = (hh1 >= 1);
  const bool v0D = (hh0 <= H_ - 2), v1D = (hh1 <= H_ - 2);
  unsigned int vo0[5], vo1[5];
  vo0[0] = base0;                                               vo1[0] = base1;
  vo0[1] = v0L ? (unsigned int)((hw0 - 1  + qh) * 4) : base0;   vo1[1] = v1L ? (unsigned int)((hw1 - 1  + qh) * 4) : base1;
  vo0[2] = v0R ? (unsigned int)((hw0 + 1  + qh) * 4) : base0;   vo1[2] = v1R ? (unsigned int)((hw1 + 1  + qh) * 4) : base1;
  vo0[3] = v0U ? (unsigned int)((hw0 - W_ + qh) * 4) : base0;   vo1[3] = v1U ? (unsigned int)((hw1 - W_ + qh) * 4) : base1;
  vo0[4] = v0D ? (unsigned int)((hw0 + W_ + qh) * 4) : base0;   vo1[4] = v1D ? (unsigned int)((hw1 + W_ + qh) * 4) : base1;
  float fm0[5], fm1[5];
  fm0[0] = 1.f;               fm1[0] = 1.f;
  fm0[1] = v0L ? 1.f : 0.f;   fm1[1] = v1L ? 1.f : 0.f;
  fm0[2] = v0R ? 1.f : 0.f;   fm1[2] = v1R ? 1.f : 0.f;
  fm0[3] = v0U ? 1.f : 0.f;   fm1[3] = v1U ? 1.f : 0.f;
  fm0[4] = v0D ? 1.f : 0.f;   fm1[4] = v1D ? 1.f : 0.f;

  const char* __restrict__ px = (const char*)(x + (size_t)bidx * CIN_ * HW_);
  const unsigned short* __restrict__ wp =
      g_wbf + (size_t)(bo * 2 + wo) * 16384 + lane * 8;

  f32x4 acc[2][4];
  #pragma unroll
  for (int a = 0; a < 2; ++a)
    #pragma unroll
    for (int b = 0; b < 4; ++b)
      acc[a][b] = (f32x4){0.f, 0.f, 0.f, 0.f};

  // ---- main loop: fully unrolled, barrier-free ----
  #pragma unroll
  for (int ks = 0; ks < 8; ++ks) {
    // W fragments (B-operand) straight from L2-resident g_wbf
    short8 wf[4];
    #pragma unroll
    for (int b = 0; b < 4; ++b)
      wf[b] = *(const short8*)(wp + ks * 2048 + b * 512);

    // x gather (A-operand): channel c = ks*32 + 4j + quad
    float fa0[8], fa1[8];
    #pragma unroll
    for (int j = 0; j < 8; ++j) {
      const int c0 = ks * 32 + 4 * j;          // compile-time after unroll
      unsigned int o0, o1; float m0, m1;
      if (c0 == 48)       { bool hi = quad >= 3;   // straddles c=51
        o0 = hi ? vo0[1] : vo0[0]; o1 = hi ? vo1[1] : vo1[0];
        m0 = hi ? fm0[1] : 1.f;    m1 = hi ? fm1[1] : 1.f; }
      else if (c0 == 100) { bool hi = quad >= 2;   // straddles c=102
        o0 = hi ? vo0[2] : vo0[1]; o1 = hi ? vo1[2] : vo1[1];
        m0 = hi ? fm0[2] : fm0[1]; m1 = hi ? fm1[2] : fm1[1]; }
      else if (c0 == 152) { bool hi = quad >= 1;   // straddles c=153
        o0 = hi ? vo0[3] : vo0[2]; o1 = hi ? vo1[3] : vo1[2];
        m0 = hi ? fm0[3] : fm0[2]; m1 = hi ? fm1[3] : fm1[2]; }
      else {
        const int r = (c0 >= 51) + (c0 >= 102) + (c0 >= 153) + (c0 >= 204);
        o0 = vo0[r]; o1 = vo1[r]; m0 = fm0[r]; m1 = fm1[r];
      }
      const unsigned int cb = (unsigned int)(c0 * HW_ * 4);
      float v0 = *(const float*)(px + (o0 + cb));
      float v1 = *(const float*)(px + (o1 + cb));
      fa0[j] = v0 * m0;
      fa1[j] = v1 * m1;
    }

    // pack to bf16 frags (RNE, verified R8)
    union { short8 v; unsigned int d[4]; } af0, af1;
    #pragma unroll
    for (int jj = 0; jj < 4; ++jj) {
      asm("v_cvt_pk_bf16_f32 %0, %1, %2" : "=v"(af0.d[jj]) : "v"(fa0[2*jj]), "v"(fa0[2*jj+1]));
      asm("v_cvt_pk_bf16_f32 %0, %1, %2" : "=v"(af1.d[jj]) : "v"(fa1[2*jj]), "v"(fa1[2*jj+1]));
    }

    #pragma unroll
    for (int b = 0; b < 4; ++b) {
      acc[0][b] = __builtin_amdgcn_mfma_f32_16x16x32_bf16(af0.v, wf[b], acc[0][b], 0, 0, 0);
      acc[1][b] = __builtin_amdgcn_mfma_f32_16x16x32_bf16(af1.v, wf[b], acc[1][b], 0, 0, 0);
    }
  }

  // ---- epilogue: BN + ReLU, wave-private LDS transpose, coalesced stores ----
  // acc layout (swapped operands): row = n = a*16 + quad*4 + r, col = o = b*16 + l15
  float invb[4], addb[4];
  #pragma unroll
  for (int b = 0; b < 4; ++b) {
    int ol = wo * 64 + b * 16 + l15;
    invb[b] = bnp[2 * ol];
    addb[b] = bnp[2 * ol + 1];
  }
  float* tb = &tbuf[wv][0];
  const size_t obase0 = (size_t)bidx * COUT_ * HW_;
  #pragma unroll
  for (int hb = 0; hb < 2; ++hb) {
    #pragma unroll
    for (int bb = 0; bb < 2; ++bb) {
      const int b = hb * 2 + bb;
      #pragma unroll
      for (int a = 0; a < 2; ++a)
        #pragma unroll
        for (int r = 0; r < 4; ++r) {
          float v = fmaxf(fmaf(acc[a][b][r], invb[b], addb[b]), 0.f);
          tb[(bb * 16 + l15) * 33 + (a * 16 + quad * 4 + r)] = v;
        }
    }
    asm volatile("s_waitcnt lgkmcnt(0)" ::: "memory");   // wave-private: no barrier
    #pragma unroll
    for (int oi = 0; oi < 16; ++oi) {
      int ol  = oi * 2 + (lane >> 5);
      int nl  = lane & 31;
      float v = tb[ol * 33 + nl];
      int og  = bo * 128 + wo * 64 + hb * 32 + ol;
      int hwg = rem + wn * 32 + nl;
      out[obase0 + (size_t)og * HW_ + hwg] = v;
    }
    asm volatile("s_waitcnt lgkmcnt(0)" ::: "memory");   // WAR before next half
  }
}

extern "C" void kernel_launch(void* const* d_in, const int* in_sizes, int n_in,
                              void* d_out, int out_size, void* d_ws, size_t ws_size,
                              hipStream_t stream) {
  const float* x     = (const float*)d_in[0];
  const float* wgt   = (const float*)d_in[1];
  const float* gamma = (const float*)d_in[2];
  const float* beta  = (const float*)d_in[3];
  const float* rmean = (const float*)d_in[4];
  const float* rvar  = (const float*)d_in[5];
  float* out = (float*)d_out;

  prep_weights<<<dim3(256), dim3(256), 0, stream>>>(wgt);
  shiftconv_gemm<<<dim3(3136), dim3(256), 0, stream>>>(x, gamma, beta, rmean, rvar, out);
}

// Round 11
// 210.253 us; speedup vs baseline: 1.1021x; 1.1021x over previous
//
#include <hip/hip_runtime.h>

#define H_ 56
#define W_ 56
#define HW_ 3136
#define CIN_ 256
#define COUT_ 256

typedef __attribute__((ext_vector_type(8))) short short8;
typedef __attribute__((ext_vector_type(4))) float f32x4;

// Pre-swizzled bf16 weights, written by prep_weights each launch (idempotent).
// Layout: [bm][kt][e], e = m*32 + col, content = bf16(W[bm*128+m][kt*32 + (col ^ swz32(m))])
__device__ unsigned short g_wbf[COUT_ * CIN_];

__device__ __forceinline__ int swz32(int n) { return ((n ^ (n >> 3)) & 3) << 3; }

__device__ __forceinline__ unsigned short f2bf(float f) {
  union { float f; unsigned int i; } v; v.f = f;
  unsigned int b = v.i + (0x7fffu + ((v.i >> 16) & 1u));  // RNE
  return (unsigned short)(b >> 16);
}

__device__ __forceinline__ void gload_lds16(const unsigned short* g, unsigned short* l) {
  __builtin_amdgcn_global_load_lds(
      (const __attribute__((address_space(1))) unsigned int*)g,
      (__attribute__((address_space(3))) unsigned int*)l, 16, 0, 0);
}

__device__ __forceinline__ void shift_decode(int c, int& dx, int& dy) {
  if (c < 102)      { dy = 0; dx = (c < 51) ? 0 : 1; }
  else if (c < 153) { dx = -1; dy = 0; }
  else if (c < 204) { dx = 0;  dy = 1; }
  else              { dx = 0;  dy = -1; }
}

__global__ __launch_bounds__(256)
void prep_weights(const float* __restrict__ wgt) {
  int idx  = blockIdx.x * 256 + threadIdx.x;   // 0..65535
  int tile = idx >> 12;                        // bm*8 + kt
  int bm = tile >> 3, kt = tile & 7;
  int e   = idx & 4095;
  int m   = e >> 5, col = e & 31;
  int o   = bm * 128 + m;
  int k   = kt * 32 + (col ^ swz32(m));
  g_wbf[idx] = f2bf(wgt[o * CIN_ + k]);
}

// Load next x slice into registers (shift applied later at LDS-write time).
__device__ __forceinline__ void load_x(const float* __restrict__ x, size_t xb,
                                       int hh, int w0, int c,
                                       float4& p0, float4& p1, float& pe) {
  int dx, dy; shift_decode(c, dx, dy);
  int h2 = hh - dy;
  p0 = make_float4(0.f, 0.f, 0.f, 0.f);
  p1 = make_float4(0.f, 0.f, 0.f, 0.f);
  pe = 0.f;
  if ((unsigned)h2 < (unsigned)H_) {
    const float* row = x + xb + (size_t)c * HW_ + h2 * W_;
    p0 = *(const float4*)(row + w0);
    p1 = *(const float4*)(row + w0 + 4);
    if (dx == 1)       { if (w0 > 0)      pe = row[w0 - 1]; }
    else if (dx == -1) { if (w0 + 8 < W_) pe = row[w0 + 8]; }
  }
}

// Apply the W-shift in registers and scatter bf16 into the (transposed) B tile.
__device__ __forceinline__ void write_b(unsigned short* __restrict__ B,
                                        int nloc0, int krow, int c,
                                        const float4& p0, const float4& p1, float pe) {
  int dx, dy; shift_decode(c, dx, dy);
  float s[8] = {p0.x, p0.y, p0.z, p0.w, p1.x, p1.y, p1.z, p1.w};
  float vals[8];
  if (dx == 0) {
    #pragma unroll
    for (int i = 0; i < 8; ++i) vals[i] = s[i];
  } else if (dx == 1) {          // y[w] = x[w-1]
    #pragma unroll
    for (int i = 7; i >= 1; --i) vals[i] = s[i - 1];
    vals[0] = pe;
  } else {                       // dx == -1: y[w] = x[w+1]
    #pragma unroll
    for (int i = 0; i < 7; ++i) vals[i] = s[i + 1];
    vals[7] = pe;
  }
  #pragma unroll
  for (int i = 0; i < 8; ++i) {
    int nl = nloc0 + i;
    B[nl * 32 + (krow ^ swz32(nl))] = f2bf(vals[i]);
  }
}

__global__ __launch_bounds__(256, 4)
void shiftconv_gemm(const float* __restrict__ x,
                    const float* __restrict__ gamma,
                    const float* __restrict__ beta,
                    const float* __restrict__ rmean,
                    const float* __restrict__ rvar,
                    float* __restrict__ out)
{
  // Double-buffered: A [128 m][32 k] bf16, B [64 n][32 k] bf16, both k-contig,
  // cols XOR-swizzled by ((row^(row>>3))&3)<<3 -> b128 frag reads conflict-free.
  __shared__ unsigned short Alds[2][128 * 32];   // 2 x 8 KB
  __shared__ unsigned short Blds[2][64 * 32];    // 2 x 4 KB
  __shared__ float bnp[256];                     // interleaved (inv, add)

  const int t = threadIdx.x;
  // ONLY change vs R2 (77.5 us): 1-D grid + bijective XCD swizzle.
  // nwg = 3136 = 8*392; XCD x (orig&7 == x under round-robin dispatch) gets the
  // contiguous wgid chunk [x*392,(x+1)*392): the bm-pair sharing an x slice
  // (wgid 2q, 2q+1) is adjacent in time on the same XCD -> x re-read L2-hits.
  const int orig = blockIdx.x;
  const int wgid = (orig & 7) * 392 + (orig >> 3);
  const int bm   = wgid & 1;     // 2 m-tiles of 128
  const int bn   = wgid >> 1;    // 1568 n-tiles of 64

  const int lane = t & 63;
  const int wv   = t >> 6;
  const int wm   = wv >> 1;      // wave m-half (64 rows)
  const int wn   = wv & 1;       // wave n-half (32 cols)
  const int quad = lane >> 4;
  const int l15  = lane & 15;

  if (t < 128) {
    int o = bm * 128 + t;
    float inv = gamma[o] * rsqrtf(rvar[o] + 1e-5f);
    bnp[2 * t]     = inv;
    bnp[2 * t + 1] = beta[o] - rmean[o] * inv;
  }

  // ---- B staging decode (constant across K loop): 8 n x 1 k per thread ----
  const int chunk  = t & 7;           // 8 chunks of 8 n
  const int krow   = t >> 3;          // 0..31 = k within tile
  const int nloc0  = chunk * 8;
  const int nglob0 = bn * 64 + nloc0;
  const int bidx   = nglob0 / HW_;
  const int rem    = nglob0 - bidx * HW_;
  const int hh     = rem / W_;
  const int w0     = rem - hh * W_;   // multiple of 8
  const size_t xb  = (size_t)bidx * CIN_ * HW_;

  // ---- A staging source: pre-swizzled bf16 weights ----
  const unsigned short* wsrc = g_wbf + bm * (8 * 4096) + t * 8;

  f32x4 acc[4][2];
  #pragma unroll
  for (int i = 0; i < 4; ++i)
    #pragma unroll
    for (int j = 0; j < 2; ++j)
      acc[i][j] = (f32x4){0.f, 0.f, 0.f, 0.f};

  float4 p0, p1;   // raw prefetched x (shift applied at write time)
  float  pe;       // edge element for dx = +/-1

  // ---- prologue: stage tile 0 ----
  {
    const unsigned short* g = wsrc;
    gload_lds16(g,        &Alds[0][wv * 512]);
    gload_lds16(g + 2048, &Alds[0][wv * 512 + 2048]);
  }
  load_x(x, xb, hh, w0, krow, p0, p1, pe);
  write_b(&Blds[0][0], nloc0, krow, krow, p0, p1, pe);
  __syncthreads();

  const int kb = quad * 8;
  int buf = 0;

  // ---- main loop: one barrier per K-tile; next tile's loads in flight over compute ----
  for (int kt = 0; kt < 8; ++kt) {
    if (kt < 7) {
      const unsigned short* g = wsrc + (kt + 1) * 4096;
      gload_lds16(g,        &Alds[buf ^ 1][wv * 512]);
      gload_lds16(g + 2048, &Alds[buf ^ 1][wv * 512 + 2048]);
      load_x(x, xb, hh, w0, (kt + 1) * 32 + krow, p0, p1, pe);
    }

    short8 af[4], bfr[2];
    #pragma unroll
    for (int f = 0; f < 4; ++f) {
      int ml = wm * 64 + f * 16 + l15;
      af[f] = *(const short8*)(&Alds[buf][ml * 32 + (kb ^ swz32(ml))]);
    }
    #pragma unroll
    for (int g2 = 0; g2 < 2; ++g2) {
      int nl2 = wn * 32 + g2 * 16 + l15;
      bfr[g2] = *(const short8*)(&Blds[buf][nl2 * 32 + (kb ^ swz32(nl2))]);
    }
    #pragma unroll
    for (int mf = 0; mf < 4; ++mf)
      #pragma unroll
      for (int nf = 0; nf < 2; ++nf)
        acc[mf][nf] = __builtin_amdgcn_mfma_f32_16x16x32_bf16(
            af[mf], bfr[nf], acc[mf][nf], 0, 0, 0);

    if (kt < 7)
      write_b(&Blds[buf ^ 1][0], nloc0, krow, (kt + 1) * 32 + krow, p0, p1, pe);

    __syncthreads();
    buf ^= 1;
  }

  // ---- epilogue: BN + ReLU + fp32 store ----
  size_t nbase[2];
  #pragma unroll
  for (int nf = 0; nf < 2; ++nf) {
    int ng  = bn * 64 + wn * 32 + nf * 16 + l15;
    int b2  = ng / HW_;
    int hw2 = ng - b2 * HW_;
    nbase[nf] = (size_t)b2 * COUT_ * HW_ + hw2;
  }
  #pragma unroll
  for (int mf = 0; mf < 4; ++mf) {
    int mloc = wm * 64 + mf * 16 + quad * 4;   // local o for reg r=0
    float inv[4], add[4];
    #pragma unroll
    for (int r = 0; r < 4; ++r) {
      inv[r] = bnp[2 * (mloc + r)];
      add[r] = bnp[2 * (mloc + r) + 1];
    }
    size_t obase = (size_t)(bm * 128 + mloc) * HW_;
    #pragma unroll
    for (int nf = 0; nf < 2; ++nf) {
      #pragma unroll
      for (int r = 0; r < 4; ++r) {
        float v = fmaf(acc[mf][nf][r], inv[r], add[r]);
        out[nbase[nf] + obase + (size_t)r * HW_] = fmaxf(v, 0.0f);
      }
    }
  }
}

extern "C" void kernel_launch(void* const* d_in, const int* in_sizes, int n_in,
                              void* d_out, int out_size, void* d_ws, size_t ws_size,
                              hipStream_t stream) {
  const float* x     = (const float*)d_in[0];
  const float* wgt   = (const float*)d_in[1];
  const float* gamma = (const float*)d_in[2];
  const float* beta  = (const float*)d_in[3];
  const float* rmean = (const float*)d_in[4];
  const float* rvar  = (const float*)d_in[5];
  float* out = (float*)d_out;

  prep_weights<<<dim3(256), dim3(256), 0, stream>>>(wgt);
  shiftconv_gemm<<<dim3(3136), dim3(256), 0, stream>>>(x, gamma, beta, rmean, rvar, out);
}